// Round 10
// baseline (5087.872 us; speedup 1.0000x reference)
//
#include <hip/hip_runtime.h>
#include <hip/hip_bf16.h>

#define Bn 64
#define Tn 1024
#define In 64
#define Dn 256

typedef short bf16x8 __attribute__((ext_vector_type(8)));
typedef unsigned short u16x8 __attribute__((ext_vector_type(8)));
typedef unsigned short u16x4 __attribute__((ext_vector_type(4)));
typedef float f32x4 __attribute__((ext_vector_type(4)));
typedef unsigned int u32x2 __attribute__((ext_vector_type(2)));

__device__ __forceinline__ unsigned short f2bf(float f){
  unsigned u = __float_as_uint(f);
  u += 0x7fffu + ((u >> 16) & 1u);       // RNE
  return (unsigned short)(u >> 16);
}
__device__ __forceinline__ float sig_(float x){ return 1.f / (1.f + __expf(-x)); }
__device__ __forceinline__ float tanh_(float x){ float e = __expf(2.f * x); return 1.f - 2.f / (e + 1.f); }

__device__ __forceinline__ bf16x8 pack8(const float* f){
  bf16x8 r;
  #pragma unroll
  for (int i = 0; i < 8; ++i) r[i] = (short)f2bf(f[i]);
  return r;
}

// Mid-chain MFMA with explicit register-class control. ONLY used between
// intrinsic bookends: MFMA->MFMA srcC chaining is hardware-interlocked, so
// no compiler hazard handling is needed here. The hazardous MFMA<->VALU
// boundaries (zero-init and EW reads) go through intrinsics, which the
// compiler instruments with the required s_nops.
__device__ __forceinline__ void mfma_va(f32x4& d, const bf16x8& a, const bf16x8& b){
  asm("v_mfma_f32_16x16x32_bf16 %0, %1, %2, %0" : "+a"(d) : "v"(a), "v"(b));
}
__device__ __forceinline__ void mfma_aa(f32x4& d, const bf16x8& a, const bf16x8& b){
  asm("v_mfma_f32_16x16x32_bf16 %0, %1, %2, %0" : "+a"(d) : "a"(a), "v"(b));
}

// ---------------------------------------------------------------------------
// gates_x: Gx = x @ Wih^T + bih + bhh, written bf16 in the scan's fragment
// layout: per (chain,t,u): [jmt 8][lane 64][gate 4]. Lane (lg,lr) of slot
// (u,j,mt) holds gates i=0..3 of dim = u*32+j*16+lg*4+mt, batch = chain*16+lr.
// ---------------------------------------------------------------------------
__global__ __launch_bounds__(256, 1) void gates_x_kernel(
    const float* __restrict__ x, const float* __restrict__ Wih,
    const float* __restrict__ bih, const float* __restrict__ bhh,
    unsigned short* __restrict__ Gx)
{
  const int bid = blockIdx.x;
  const int chain = bid >> 8;
  const int t0 = (bid & 255) * 4;
  const int tid = threadIdx.x;
  const int wv = tid >> 6;
  const int l = tid & 63;
  const int lr = l & 15, lg = l >> 4;
  const int gate = lr & 3, dimx = lr >> 2;

  __shared__ float bsum[1024];
  for (int r = tid; r < 1024; r += 256) bsum[r] = bih[r] + bhh[r];
  __syncthreads();

  bf16x8 wa[16][2];
  #pragma unroll
  for (int up = 0; up < 2; ++up)
    #pragma unroll
    for (int j = 0; j < 2; ++j)
      #pragma unroll
      for (int mt = 0; mt < 4; ++mt){
        const int u = wv * 2 + up;
        const int row = gate * Dn + u * 32 + j * 16 + dimx * 4 + mt;
        #pragma unroll
        for (int kt = 0; kt < 2; ++kt){
          float tmp[8];
          *(float4*)&tmp[0] = *(const float4*)&Wih[row * In + kt * 32 + lg * 8];
          *(float4*)&tmp[4] = *(const float4*)&Wih[row * In + kt * 32 + lg * 8 + 4];
          wa[(up * 2 + j) * 4 + mt][kt] = pack8(tmp);
        }
      }

  const int b = chain * 16 + lr;
  for (int tt = 0; tt < 4; ++tt){
    const int t = t0 + tt;
    bf16x8 xb[2];
    #pragma unroll
    for (int kt = 0; kt < 2; ++kt){
      float tmp[8];
      *(float4*)&tmp[0] = *(const float4*)&x[(size_t)(b * Tn + t) * In + kt * 32 + lg * 8];
      *(float4*)&tmp[4] = *(const float4*)&x[(size_t)(b * Tn + t) * In + kt * 32 + lg * 8 + 4];
      xb[kt] = pack8(tmp);
    }
    #pragma unroll
    for (int up = 0; up < 2; ++up)
      #pragma unroll
      for (int j = 0; j < 2; ++j)
        #pragma unroll
        for (int mt = 0; mt < 4; ++mt){
          const int u = wv * 2 + up;
          f32x4 a = {0.f, 0.f, 0.f, 0.f};
          a = __builtin_amdgcn_mfma_f32_16x16x32_bf16(wa[(up*2+j)*4+mt][0], xb[0], a, 0, 0, 0);
          a = __builtin_amdgcn_mfma_f32_16x16x32_bf16(wa[(up*2+j)*4+mt][1], xb[1], a, 0, 0, 0);
          const int dim = u * 32 + j * 16 + lg * 4 + mt;
          u16x4 o;
          #pragma unroll
          for (int i = 0; i < 4; ++i) o[i] = f2bf(a[i] + bsum[i * Dn + dim]);
          const size_t off = (((size_t)(chain * Tn + t) * 8 + u) * 8 + (j * 4 + mt)) * 256
                             + (lg * 16 + lr) * 4;
          *(u16x4*)&Gx[off] = o;
        }
  }
}

// ---------------------------------------------------------------------------
// LSTM scan v10 = v9 residency + intrinsic bookends (hazard fix).
// 4 WGs (one per 16-batch chain) x 512 threads, zero inter-CU communication.
// Per-wave weight residency (64 units of bf16x8):
//   arch VGPR 16 units (kt0,kt7 of all 8 tiles)   -> intrinsic bookends
//   AGPR      29 units (A.kt1-6 x4 + B.mt0.kt1-5) -> asm "a"
//   LDS       19 units (B.mt0.kt6 + B.mt1-3.kt1-6)-> asm "v" from ds_read
// acc in AGPRs: AGPR 116+16=132, arch ~105, total ~237 <= 256 unified.
// hL single-buffered (8 KB): LDS = 152+8 = 160 KiB exact. 2 barriers/step.
// ---------------------------------------------------------------------------
__global__ __launch_bounds__(512, 1) void lstm_scan_kernel(
    const unsigned short* __restrict__ Gx, const float* __restrict__ Whh,
    unsigned short* __restrict__ Hbf)
{
  const int chain = blockIdx.x;
  const int tid = threadIdx.x;
  const int u = tid >> 6;
  const int l = tid & 63;
  const int lr = l & 15, lg = l >> 4;
  const int gate = lr & 3, dimx = lr >> 2;

  __shared__ unsigned short WL[8][19 * 512];   // 152 KB
  __shared__ unsigned short hL[32][16][8];     // 8 KB

  auto ldw = [&](int row, int kt) -> bf16x8 {
    float tmp[8];
    *(float4*)&tmp[0] = *(const float4*)&Whh[row * Dn + kt * 32 + lg * 8];
    *(float4*)&tmp[4] = *(const float4*)&Whh[row * Dn + kt * 32 + lg * 8 + 4];
    return pack8(tmp);
  };

  bf16x8 wA[16];   // arch-resident bookend weights
  bf16x8 wG[29];   // AGPR-resident mid-chain weights
  {
    const int rA = gate * Dn + u * 32 + dimx * 4;        // pass A rows: +mt
    const int rB = rA + 16;                              // pass B rows: +mt
    #pragma unroll
    for (int mt = 0; mt < 4; ++mt){
      wA[mt]      = ldw(rA + mt, 0);   // A bookend kt0
      wA[4 + mt]  = ldw(rA + mt, 7);   // A bookend kt7
      wA[8 + mt]  = ldw(rB + mt, 0);   // B bookend kt0
      wA[12 + mt] = ldw(rB + mt, 7);   // B bookend kt7
      #pragma unroll
      for (int kt = 1; kt < 7; ++kt)
        wG[mt * 6 + kt - 1] = ldw(rA + mt, kt);          // A mid
    }
    #pragma unroll
    for (int kt = 1; kt < 6; ++kt)
      wG[24 + kt - 1] = ldw(rB + 0, kt);                 // B.mt0 kt1..5
    // class-pin the AGPR weights once (all later uses are "a")
    #pragma unroll
    for (int i = 0; i < 29; ++i) asm("" : "+a"(wG[i]));
    // LDS units: 0 = B.mt0.kt6; 1+(mt-1)*6+(kt-1) = B.mt(1..3).kt(1..6)
    *(bf16x8*)&WL[u][0 * 512 + lg * 128 + lr * 8] = ldw(rB + 0, 6);
    #pragma unroll
    for (int mt = 1; mt < 4; ++mt)
      #pragma unroll
      for (int kt = 1; kt < 7; ++kt)
        *(bf16x8*)&WL[u][(1 + (mt - 1) * 6 + (kt - 1)) * 512 + lg * 128 + lr * 8]
            = ldw(rB + mt, kt);
  }
  for (int i = tid; i < 32 * 16 * 8 / 2; i += 512) ((unsigned*)hL)[i] = 0u;
  __syncthreads();

  float cst[8] = {0.f, 0.f, 0.f, 0.f, 0.f, 0.f, 0.f, 0.f};
  const int lane64 = lg * 16 + lr;
  const size_t hbB = (size_t)(chain * 16 + lr) * Tn * Dn;
  const int db0 = u * 4 + (lg >> 1);
  const int hoff = (lg & 1) * 4;
  const f32x4 zz = {0.f, 0.f, 0.f, 0.f};

  for (int t = 0; t < Tn; ++t){
    const unsigned short* gxp = Gx + ((size_t)(chain * Tn + t) * 8 + u) * 2048;

    u32x2 gA[4];
    #pragma unroll
    for (int jm = 0; jm < 4; ++jm)
      gA[jm] = *(const u32x2*)&gxp[jm * 256 + lane64 * 4];

    // ---- pass A (j=0 dims) ----
    f32x4 acc[4];
    {   // kt=0 bookend (intrinsic: compiler owns zero-init + hazards)
      const bf16x8 hf = *(const bf16x8*)&hL[lg][lr][0];
      acc[0] = __builtin_amdgcn_mfma_f32_16x16x32_bf16(wA[0], hf, zz, 0, 0, 0);
      acc[1] = __builtin_amdgcn_mfma_f32_16x16x32_bf16(wA[1], hf, zz, 0, 0, 0);
      acc[2] = __builtin_amdgcn_mfma_f32_16x16x32_bf16(wA[2], hf, zz, 0, 0, 0);
      acc[3] = __builtin_amdgcn_mfma_f32_16x16x32_bf16(wA[3], hf, zz, 0, 0, 0);
    }
    #pragma unroll
    for (int kt = 1; kt < 7; ++kt){   // mid chain: MFMA->MFMA only
      const bf16x8 hf = *(const bf16x8*)&hL[kt * 4 + lg][lr][0];
      mfma_aa(acc[0], wG[0  + kt - 1], hf);
      mfma_aa(acc[1], wG[6  + kt - 1], hf);
      mfma_aa(acc[2], wG[12 + kt - 1], hf);
      mfma_aa(acc[3], wG[18 + kt - 1], hf);
    }
    {   // kt=7 bookend (intrinsic: compiler inserts MFMA->VALU nops for EW)
      const bf16x8 hf = *(const bf16x8*)&hL[28 + lg][lr][0];
      acc[0] = __builtin_amdgcn_mfma_f32_16x16x32_bf16(wA[4], hf, acc[0], 0, 0, 0);
      acc[1] = __builtin_amdgcn_mfma_f32_16x16x32_bf16(wA[5], hf, acc[1], 0, 0, 0);
      acc[2] = __builtin_amdgcn_mfma_f32_16x16x32_bf16(wA[6], hf, acc[2], 0, 0, 0);
      acc[3] = __builtin_amdgcn_mfma_f32_16x16x32_bf16(wA[7], hf, acc[3], 0, 0, 0);
    }
    unsigned long long hq0 = 0;
    #pragma unroll
    for (int mt = 0; mt < 4; ++mt){
      const unsigned glo = gA[mt][0], ghi = gA[mt][1];
      const float gi = __uint_as_float(glo << 16)         + acc[mt][0];
      const float gf = __uint_as_float(glo & 0xFFFF0000u) + acc[mt][1];
      const float gg = __uint_as_float(ghi << 16)         + acc[mt][2];
      const float go = __uint_as_float(ghi & 0xFFFF0000u) + acc[mt][3];
      const float ig = sig_(gi), fg = sig_(gf), gv = tanh_(gg), og = sig_(go);
      const float c = fg * cst[mt] + ig * gv;
      cst[mt] = c;
      hq0 |= (unsigned long long)f2bf(og * tanh_(c)) << (16 * mt);
    }

    u32x2 gB[4];
    #pragma unroll
    for (int jm = 0; jm < 4; ++jm)
      gB[jm] = *(const u32x2*)&gxp[(4 + jm) * 256 + lane64 * 4];

    // ---- pass B (j=1 dims) ----
    {   // kt=0 bookend
      const bf16x8 hf = *(const bf16x8*)&hL[lg][lr][0];
      acc[0] = __builtin_amdgcn_mfma_f32_16x16x32_bf16(wA[8],  hf, zz, 0, 0, 0);
      acc[1] = __builtin_amdgcn_mfma_f32_16x16x32_bf16(wA[9],  hf, zz, 0, 0, 0);
      acc[2] = __builtin_amdgcn_mfma_f32_16x16x32_bf16(wA[10], hf, zz, 0, 0, 0);
      acc[3] = __builtin_amdgcn_mfma_f32_16x16x32_bf16(wA[11], hf, zz, 0, 0, 0);
    }
    #pragma unroll
    for (int kt = 1; kt < 7; ++kt){
      const bf16x8 hf = *(const bf16x8*)&hL[kt * 4 + lg][lr][0];
      if (kt < 6) mfma_aa(acc[0], wG[24 + kt - 1], hf);
      else        mfma_va(acc[0], *(const bf16x8*)&WL[u][0 * 512 + lg * 128 + lr * 8], hf);
      mfma_va(acc[1], *(const bf16x8*)&WL[u][(1 + 0 * 6 + kt - 1) * 512 + lg * 128 + lr * 8], hf);
      mfma_va(acc[2], *(const bf16x8*)&WL[u][(1 + 1 * 6 + kt - 1) * 512 + lg * 128 + lr * 8], hf);
      mfma_va(acc[3], *(const bf16x8*)&WL[u][(1 + 2 * 6 + kt - 1) * 512 + lg * 128 + lr * 8], hf);
    }
    {   // kt=7 bookend
      const bf16x8 hf = *(const bf16x8*)&hL[28 + lg][lr][0];
      acc[0] = __builtin_amdgcn_mfma_f32_16x16x32_bf16(wA[12], hf, acc[0], 0, 0, 0);
      acc[1] = __builtin_amdgcn_mfma_f32_16x16x32_bf16(wA[13], hf, acc[1], 0, 0, 0);
      acc[2] = __builtin_amdgcn_mfma_f32_16x16x32_bf16(wA[14], hf, acc[2], 0, 0, 0);
      acc[3] = __builtin_amdgcn_mfma_f32_16x16x32_bf16(wA[15], hf, acc[3], 0, 0, 0);
    }
    unsigned long long hq1 = 0;
    #pragma unroll
    for (int mt = 0; mt < 4; ++mt){
      const unsigned glo = gB[mt][0], ghi = gB[mt][1];
      const float gi = __uint_as_float(glo << 16)         + acc[mt][0];
      const float gf = __uint_as_float(glo & 0xFFFF0000u) + acc[mt][1];
      const float gg = __uint_as_float(ghi << 16)         + acc[mt][2];
      const float go = __uint_as_float(ghi & 0xFFFF0000u) + acc[mt][3];
      const float ig = sig_(gi), fg = sig_(gf), gv = tanh_(gg), og = sig_(go);
      const float c = fg * cst[4 + mt] + ig * gv;
      cst[4 + mt] = c;
      hq1 |= (unsigned long long)f2bf(og * tanh_(c)) << (16 * mt);
    }

    __syncthreads();                                   // B1: all hL reads done
    *(unsigned long long*)&hL[db0][lr][hoff]     = hq0;
    *(unsigned long long*)&hL[db0 + 2][lr][hoff] = hq1;
    __syncthreads();                                   // B2: hL(t) visible
    // history stores: drain overlaps next step's compute
    *(unsigned long long*)&Hbf[hbB + (size_t)t * Dn + u * 32 + lg * 4]      = hq0;
    *(unsigned long long*)&Hbf[hbB + (size_t)t * Dn + u * 32 + 16 + lg * 4] = hq1;
  }
}

// ---------------------------------------------------------------------------
// Flash attention, Q=K=V=H (bf16), unscaled, causal. One WG per (b, 64-row qtile).
// ---------------------------------------------------------------------------
__global__ __launch_bounds__(256, 1) void attn_kernel(
    const unsigned short* __restrict__ Hbf, unsigned short* __restrict__ ctxbf)
{
  const int bid = blockIdx.x;
  const int b = bid >> 4, qt = bid & 15;
  const int q0 = qt * 64;
  const int tid = threadIdx.x;
  const int w = tid >> 6, l = tid & 63;
  const int lr = l & 15, lg = l >> 4;

  __shared__ unsigned short Qs[64 * 256];
  __shared__ unsigned short Ks[64 * 256];
  __shared__ unsigned short Vt[256 * 64];   // transposed: [d][s]
  __shared__ unsigned short Ps[64 * 64];

  {
    const int r = tid >> 2, cs = (tid & 3) * 64;
    #pragma unroll
    for (int jj = 0; jj < 8; ++jj){
      const int c = cs + jj * 8;
      u16x8 v = *(const u16x8*)&Hbf[(b * Tn + q0 + r) * Dn + c];
      *(u16x8*)((char*)Qs + (((r * 256 + c) * 2) ^ ((r & 7) << 4))) = v;
    }
  }
  __syncthreads();
  bf16x8 qf[8];
  #pragma unroll
  for (int kc = 0; kc < 8; ++kc){
    const int r = w * 16 + lr, c = kc * 32 + lg * 8;
    qf[kc] = *(const bf16x8*)((const char*)Qs + (((r * 256 + c) * 2) ^ ((r & 7) << 4)));
  }

  float m_i[4], l_i[4];
  f32x4 o_acc[16];
  #pragma unroll
  for (int i = 0; i < 4; ++i){ m_i[i] = -__builtin_inff(); l_i[i] = 0.f; }
  #pragma unroll
  for (int n = 0; n < 16; ++n) o_acc[n] = (f32x4){0.f, 0.f, 0.f, 0.f};

  for (int kt = 0; kt <= qt; ++kt){
    const int s0 = kt * 64;
    __syncthreads();
    {
      const int r = tid >> 2, cs = (tid & 3) * 64;
      #pragma unroll
      for (int jj = 0; jj < 8; ++jj){
        const int c = cs + jj * 8;
        u16x8 v = *(const u16x8*)&Hbf[(b * Tn + s0 + r) * Dn + c];
        *(u16x8*)((char*)Ks + (((r * 256 + c) * 2) ^ ((r & 7) << 4))) = v;
      }
    }
    {
      const int s = tid & 63, db = tid >> 6;
      #pragma unroll
      for (int jj = 0; jj < 8; ++jj){
        const int d0 = db * 64 + jj * 8;
        u16x8 v = *(const u16x8*)&Hbf[(b * Tn + s0 + s) * Dn + d0];
        #pragma unroll
        for (int e = 0; e < 8; ++e){
          const int d = d0 + e;
          *(unsigned short*)((char*)Vt + (((d * 64 + s) * 2) ^ ((d & 7) << 4))) = (unsigned short)v[e];
        }
      }
    }
    __syncthreads();
    f32x4 sacc[4];
    #pragma unroll
    for (int n = 0; n < 4; ++n) sacc[n] = (f32x4){0.f, 0.f, 0.f, 0.f};
    #pragma unroll
    for (int kc = 0; kc < 8; ++kc){
      #pragma unroll
      for (int n = 0; n < 4; ++n){
        const int r = n * 16 + lr, c = kc * 32 + lg * 8;
        bf16x8 kfr = *(const bf16x8*)((const char*)Ks + (((r * 256 + c) * 2) ^ ((r & 7) << 4)));
        sacc[n] = __builtin_amdgcn_mfma_f32_16x16x32_bf16(qf[kc], kfr, sacc[n], 0, 0, 0);
      }
    }
    if (kt == qt){
      #pragma unroll
      for (int n = 0; n < 4; ++n)
        #pragma unroll
        for (int i = 0; i < 4; ++i){
          const int scol = s0 + n * 16 + lr;
          const int qrow = q0 + w * 16 + lg * 4 + i;
          if (scol > qrow) sacc[n][i] = -__builtin_inff();
        }
    }
    float rmax[4], alpha[4], rsum[4];
    #pragma unroll
    for (int i = 0; i < 4; ++i){
      float vv = fmaxf(fmaxf(sacc[0][i], sacc[1][i]), fmaxf(sacc[2][i], sacc[3][i]));
      vv = fmaxf(vv, __shfl_xor(vv, 1));
      vv = fmaxf(vv, __shfl_xor(vv, 2));
      vv = fmaxf(vv, __shfl_xor(vv, 4));
      vv = fmaxf(vv, __shfl_xor(vv, 8));
      rmax[i] = vv;
    }
    #pragma unroll
    for (int i = 0; i < 4; ++i){
      const float mn = fmaxf(m_i[i], rmax[i]);
      alpha[i] = __expf(m_i[i] - mn);
      m_i[i] = mn;
      rsum[i] = 0.f;
    }
    #pragma unroll
    for (int n = 0; n < 4; ++n){
      #pragma unroll
      for (int i = 0; i < 4; ++i){
        const float pv = __expf(sacc[n][i] - m_i[i]);
        rsum[i] += pv;
        const int r = w * 16 + lg * 4 + i, c = n * 16 + lr;
        *(unsigned short*)((char*)Ps + (((r * 64 + c) * 2) ^ ((r & 7) << 4))) = f2bf(pv);
      }
    }
    #pragma unroll
    for (int i = 0; i < 4; ++i){
      float vv = rsum[i];
      vv += __shfl_xor(vv, 1);
      vv += __shfl_xor(vv, 2);
      vv += __shfl_xor(vv, 4);
      vv += __shfl_xor(vv, 8);
      l_i[i] = l_i[i] * alpha[i] + vv;
    }
    #pragma unroll
    for (int n = 0; n < 16; ++n)
      #pragma unroll
      for (int i = 0; i < 4; ++i) o_acc[n][i] *= alpha[i];
    #pragma unroll
    for (int kc = 0; kc < 2; ++kc){
      const int r = w * 16 + lr, c = kc * 32 + lg * 8;
      bf16x8 pfr = *(const bf16x8*)((const char*)Ps + (((r * 64 + c) * 2) ^ ((r & 7) << 4)));
      #pragma unroll
      for (int n = 0; n < 16; ++n){
        const int vr = n * 16 + lr, vc = kc * 32 + lg * 8;
        bf16x8 vfr = *(const bf16x8*)((const char*)Vt + (((vr * 64 + vc) * 2) ^ ((vr & 7) << 4)));
        o_acc[n] = __builtin_amdgcn_mfma_f32_16x16x32_bf16(pfr, vfr, o_acc[n], 0, 0, 0);
      }
    }
  }
  #pragma unroll
  for (int n = 0; n < 16; ++n)
    #pragma unroll
    for (int i = 0; i < 4; ++i){
      const float vv = o_acc[n][i] / l_i[i];
      const int q = q0 + w * 16 + lg * 4 + i;
      const int d = n * 16 + lr;
      ctxbf[(b * Tn + q) * Dn + d] = f2bf(vv);
    }
}

// ---------------------------------------------------------------------------
// MLP: out = relu([H|ctx] @ W1^T + b1) @ W2^T + b2, fused per 64-row M tile.
// ---------------------------------------------------------------------------
__global__ __launch_bounds__(256, 1) void mlp_kernel(
    const unsigned short* __restrict__ Hbf, const unsigned short* __restrict__ ctxbf,
    const float* __restrict__ W1, const float* __restrict__ b1,
    const float* __restrict__ W2, const float* __restrict__ b2,
    float* __restrict__ out)
{
  const int m0 = blockIdx.x * 64;
  const int tid = threadIdx.x;
  const int w = tid >> 6, l = tid & 63;
  const int lr = l & 15, lg = l >> 4;

  __shared__ unsigned short As[64 * 512];
  __shared__ unsigned short Ws[64 * 512];

  {
    const int r = tid >> 2, cs = (tid & 3) * 128;
    #pragma unroll
    for (int jj = 0; jj < 16; ++jj){
      const int c = cs + jj * 8;
      u16x8 v;
      if (c < 256) v = *(const u16x8*)&Hbf[(m0 + r) * Dn + c];
      else         v = *(const u16x8*)&ctxbf[(m0 + r) * Dn + (c - 256)];
      *(u16x8*)((char*)As + (((r * 512 + c) * 2) ^ ((r & 7) << 4))) = v;
    }
  }
  f32x4 hacc[16];
  #pragma unroll
  for (int n = 0; n < 16; ++n) hacc[n] = (f32x4){0.f, 0.f, 0.f, 0.f};

  for (int nb = 0; nb < 4; ++nb){
    __syncthreads();
    {
      const int r = tid >> 2, cs = (tid & 3) * 128;
      #pragma unroll
      for (int jj = 0; jj < 32; ++jj){
        const int c = cs + jj * 4;
        const float4 v = *(const float4*)&W1[(nb * 64 + r) * 512 + c];
        u16x4 pk = { f2bf(v.x), f2bf(v.y), f2bf(v.z), f2bf(v.w) };
        *(u16x4*)((char*)Ws + (((r * 512 + c) * 2) ^ ((r & 7) << 4))) = pk;
      }
    }
    __syncthreads();
    #pragma unroll
    for (int kc = 0; kc < 16; ++kc){
      const int ar = w * 16 + lr, ac = kc * 32 + lg * 8;
      bf16x8 af = *(const bf16x8*)((const char*)As + (((ar * 512 + ac) * 2) ^ ((ar & 7) << 4)));
      #pragma unroll
      for (int n = 0; n < 4; ++n){
        const int br = n * 16 + lr;
        bf16x8 bf = *(const bf16x8*)((const char*)Ws + (((br * 512 + ac) * 2) ^ ((br & 7) << 4)));
        hacc[nb * 4 + n] = __builtin_amdgcn_mfma_f32_16x16x32_bf16(af, bf, hacc[nb * 4 + n], 0, 0, 0);
      }
    }
  }
  __syncthreads();
  #pragma unroll
  for (int nn = 0; nn < 16; ++nn){
    const int col = (nn >> 2) * 64 + (nn & 3) * 16 + lr;
    const float bv = b1[col];
    #pragma unroll
    for (int i = 0; i < 4; ++i){
      float v = hacc[nn][i] + bv;
      v = v > 0.f ? v : 0.f;
      const int r = w * 16 + lg * 4 + i;
      *(unsigned short*)((char*)As + (((r * 256 + col) * 2) ^ ((r & 7) << 4))) = f2bf(v);
    }
  }
  {
    const int r = tid >> 2, cs = (tid & 3) * 64;
    #pragma unroll
    for (int jj = 0; jj < 16; ++jj){
      const int c = cs + jj * 4;
      const float4 v = *(const float4*)&W2[r * 256 + c];
      u16x4 pk = { f2bf(v.x), f2bf(v.y), f2bf(v.z), f2bf(v.w) };
      *(u16x4*)((char*)Ws + (((r * 256 + c) * 2) ^ ((r & 7) << 4))) = pk;
    }
  }
  __syncthreads();
  f32x4 oacc[4];
  #pragma unroll
  for (int n = 0; n < 4; ++n) oacc[n] = (f32x4){0.f, 0.f, 0.f, 0.f};
  #pragma unroll
  for (int kc = 0; kc < 8; ++kc){
    const int ar = w * 16 + lr, ac = kc * 32 + lg * 8;
    bf16x8 af = *(const bf16x8*)((const char*)As + (((ar * 256 + ac) * 2) ^ ((ar & 7) << 4)));
    #pragma unroll
    for (int n = 0; n < 4; ++n){
      const int br = n * 16 + lr;
      bf16x8 bf = *(const bf16x8*)((const char*)Ws + (((br * 256 + ac) * 2) ^ ((br & 7) << 4)));
      oacc[n] = __builtin_amdgcn_mfma_f32_16x16x32_bf16(af, bf, oacc[n], 0, 0, 0);
    }
  }
  #pragma unroll
  for (int n = 0; n < 4; ++n)
    #pragma unroll
    for (int i = 0; i < 4; ++i){
      const int ii = n * 16 + lr;
      const int m = m0 + w * 16 + lg * 4 + i;
      out[m * In + ii] = oacc[n][i] + b2[ii];
    }
}

extern "C" void kernel_launch(void* const* d_in, const int* in_sizes, int n_in,
                              void* d_out, int out_size, void* d_ws, size_t ws_size,
                              hipStream_t stream)
{
  (void)in_sizes; (void)n_in; (void)out_size; (void)ws_size;
  const float* x   = (const float*)d_in[0];
  const float* Wih = (const float*)d_in[1];
  const float* Whh = (const float*)d_in[2];
  const float* bih = (const float*)d_in[3];
  const float* bhh = (const float*)d_in[4];
  const float* W1  = (const float*)d_in[5];
  const float* b1  = (const float*)d_in[6];
  const float* W2  = (const float*)d_in[7];
  const float* b2  = (const float*)d_in[8];
  float* out = (float*)d_out;

  char* ws = (char*)d_ws;
  unsigned short* Hbf   = (unsigned short*)ws;                              // [0, 32M)
  unsigned short* ctxbf = (unsigned short*)(ws + (size_t)32 * 1024 * 1024); // [32M, 64M) attn out
  unsigned short* Gx    = (unsigned short*)(ws + (size_t)32 * 1024 * 1024); // [32M, 160M)
  // Gx is fully consumed by the scan BEFORE attn writes ctx over its head.

  gates_x_kernel<<<1024, 256, 0, stream>>>(x, Wih, bih, bhh, Gx);
  lstm_scan_kernel<<<4, 512, 0, stream>>>(Gx, Whh, Hbf);
  attn_kernel<<<Bn * 16, 256, 0, stream>>>(Hbf, ctxbf);
  mlp_kernel<<<(Bn * Tn) / 64, 256, 0, stream>>>(Hbf, ctxbf, W1, b1, W2, b2, out);
}